// Round 8
// baseline (1514.047 us; speedup 1.0000x reference)
//
#include <hip/hip_runtime.h>
#include <float.h>
#include <stdint.h>

#define QN 8
#define KN 1024
#define DN 64
// Packed-key scan margin: 2*(e_pack + e_scan) = 2*(0.00390625 + ~2.5e-4) ~= 0.0083.
// MARGIN 0.01 gives slack; |b1|>=B1CAP falls back to the exact deep path so the
// e_pack<=2^-8 bound (valid for |s|<128) always applies to the codes that matter.
#define MARGIN  1.0e-2f
#define B1CAP   119.0f
#define KEYMASK 0xFFFFFE00u   // clear low 9 bits (local index space: 512 codes/lane)

typedef float    f32x16 __attribute__((ext_vector_type(16)));
typedef _Float16 f16x8  __attribute__((ext_vector_type(8)));

union AB8 { uint4 v; uint32_t u[4]; f16x8 h; };

// ===================== FROZEN reference-emulation machinery =====================
__device__ __forceinline__ float np_sumsq64(const float* a) {
    float p[DN];
    #pragma unroll
    for (int t = 0; t < DN; ++t) p[t] = __fmul_rn(a[t], a[t]);
    float l1[32];
    #pragma unroll
    for (int t = 0; t < 32; ++t) l1[t] = __fadd_rn(p[t], p[t + 32]);
    float l2[16];
    #pragma unroll
    for (int t = 0; t < 16; ++t) l2[t] = __fadd_rn(l1[t], l1[t + 16]);
    float l3[8];
    #pragma unroll
    for (int t = 0; t < 8; ++t) l3[t] = __fadd_rn(l2[t], l2[t + 8]);
    float l4[4];
    #pragma unroll
    for (int t = 0; t < 4; ++t) l4[t] = __fadd_rn(l3[t], l3[t + 4]);
    const float l5a = __fadd_rn(l4[0], l4[2]);
    const float l5b = __fadd_rn(l4[1], l4[3]);
    return __fadd_rn(l5a, l5b);
}

// Frozen rr butterfly tree over a full 64-dim residual (identical op sequence).
__device__ __forceinline__ float rr_tree(const float rex[DN]) {
    float l1[32];
    #pragma unroll
    for (int t = 0; t < 32; ++t)
        l1[t] = __fadd_rn(__fmul_rn(rex[t], rex[t]), __fmul_rn(rex[t+32], rex[t+32]));
    float l2[16];
    #pragma unroll
    for (int t = 0; t < 16; ++t) l2[t] = __fadd_rn(l1[t], l1[t + 16]);
    float l3[8];
    #pragma unroll
    for (int t = 0; t < 8; ++t) l3[t] = __fadd_rn(l2[t], l2[t + 8]);
    float l4[4];
    #pragma unroll
    for (int t = 0; t < 4; ++t) l4[t] = __fadd_rn(l3[t], l3[t + 4]);
    return __fadd_rn(__fadd_rn(l4[0], l4[2]), __fadd_rn(l4[1], l4[3]));
}
// ===============================================================================

// ---------- Phase A: exact ||c||^2 + split-fp16(-2c) codebook in fragment order ----------
__global__ __launch_bounds__(256) void rvq_prep_kernel(const float* __restrict__ cb,
                                                       uint32_t* __restrict__ apackH,
                                                       uint32_t* __restrict__ apackL,
                                                       float* __restrict__ cn) {
    const int cidx = (int)blockIdx.x * 256 + (int)threadIdx.x;
    if (cidx >= QN * KN) return;
    float row[DN];
    const float4* cp = (const float4*)(cb + (size_t)cidx * DN);
    #pragma unroll
    for (int d4 = 0; d4 < DN / 4; ++d4) {
        const float4 v = cp[d4];
        row[4*d4+0] = v.x; row[4*d4+1] = v.y; row[4*d4+2] = v.z; row[4*d4+3] = v.w;
    }
    cn[cidx] = np_sumsq64(row);                       // frozen exact ||c||^2

    const int j = cidx >> 10, local = cidx & 1023;
    const int c = local >> 5, col = local & 31;
    #pragma unroll
    for (int kk = 0; kk < 4; ++kk) {
        #pragma unroll
        for (int hh = 0; hh < 2; ++hh) {
            AB8 uh, ul;
            #pragma unroll
            for (int e = 0; e < 8; ++e) {
                const float v = -2.0f * row[kk * 16 + hh * 8 + e];   // exact (x2, negate)
                const _Float16 hi = (_Float16)v;
                const float hr = (float)hi;
                const _Float16 lo = (_Float16)__fsub_rn(v, hr);
                uh.h[e] = hi; ul.h[e] = lo;
            }
            const size_t off = (((size_t)(j * 32 + c) * 4 + kk) * 256
                                + (((hh << 5) | col) << 2));
            *(uint4*)(apackH + off) = uh.v;
            *(uint4*)(apackL + off) = ul.v;
        }
    }
}

__device__ __forceinline__ void splitpack2(float a, float b, uint32_t& H, uint32_t& L) {
    const _Float16 ah = (_Float16)a; const float ar = (float)ah;
    const _Float16 al = (_Float16)__fsub_rn(a, ar);
    const _Float16 bh = (_Float16)b; const float br = (float)bh;
    const _Float16 bl = (_Float16)__fsub_rn(b, br);
    H = (uint32_t)__builtin_bit_cast(uint16_t, ah)
      | ((uint32_t)__builtin_bit_cast(uint16_t, bh) << 16);
    L = (uint32_t)__builtin_bit_cast(uint16_t, al)
      | ((uint32_t)__builtin_bit_cast(uint16_t, bl) << 16);
}

// (val, idx) insert into sorted (b1..b4, i1..i3) — used only for the 4-value half-merge.
#define INS4IX(v, i) do {                                                    \
    const bool lt1 = (v) < b1, lt2 = (v) < b2, lt3 = (v) < b3;               \
    b4 = __builtin_amdgcn_fmed3f((v), b3, b4);                               \
    b3 = __builtin_amdgcn_fmed3f((v), b2, b3); i3 = lt2 ? i2 : (lt3 ? (i) : i3); \
    b2 = __builtin_amdgcn_fmed3f((v), b1, b2); i2 = lt1 ? i1 : (lt2 ? (i) : i2); \
    b1 = fminf((v), b1);                       i1 = lt1 ? (i) : i1;          \
} while (0)

// ---------- Main: packed-key top-4 MFMA scan, register-exact residual ----------
// r7 foundation: 1 column group/wave, lanes l & l^32 own vector (l&31), each holds its
// 32-dim K-half of x and running q (reference-exact fadd chain). New: scores carry a
// 9-bit local code index in their low mantissa bits -> top-4 tracking is 4 independent
// min/med3 chains (no cmp/cndmask per value). Light rescue = in-register exact rescore
// of {i1,i2,i3}; deep (4-way tie / |b1|>=CAP) = wave-cooperative exact full scan.
__global__ __launch_bounds__(256, 3) void rvq_encode_kernel(
    const float* __restrict__ x, const float* __restrict__ cb,
    const uint32_t* __restrict__ apackH, const uint32_t* __restrict__ apackL,
    const float* __restrict__ cnref,
    float* __restrict__ out_enc, float* __restrict__ out_q, int n) {
    const int tid  = (int)threadIdx.x;
    const int lane = tid & 63;
    const int wid  = tid >> 6;
    const int h    = lane >> 5;          // K-half this lane supplies
    const int iv   = (int)blockIdx.x * 128 + wid * 32 + (lane & 31);
    const int ivs  = iv < n ? iv : (n - 1);
    const float* xrow = x + (size_t)ivs * DN;

    // own half of x and q: slot kk*8+e <-> dim kk*16+8h+e
    float x_[32], q_[32];
    #pragma unroll
    for (int kk = 0; kk < 4; ++kk) {
        const float4 a = *(const float4*)(xrow + kk * 16 + 8 * h);
        const float4 b = *(const float4*)(xrow + kk * 16 + 8 * h + 4);
        x_[kk*8+0] = a.x; x_[kk*8+1] = a.y; x_[kk*8+2] = a.z; x_[kk*8+3] = a.w;
        x_[kk*8+4] = b.x; x_[kk*8+5] = b.y; x_[kk*8+6] = b.z; x_[kk*8+7] = b.w;
    }
    #pragma unroll
    for (int t = 0; t < 32; ++t) q_[t] = 0.f;

    int codes[QN];

    #pragma unroll 1
    for (int j = 0; j < QN; ++j) {
        // ---- exact residual (reference chain) + split-fp16 pack ----
        uint32_t bhU[16], blU[16];
        #pragma unroll
        for (int kk = 0; kk < 4; ++kk)
            #pragma unroll
            for (int m = 0; m < 4; ++m) {
                const float ra = __fsub_rn(x_[kk*8+2*m],   q_[kk*8+2*m]);
                const float rb = __fsub_rn(x_[kk*8+2*m+1], q_[kk*8+2*m+1]);
                splitpack2(ra, rb, bhU[kk*4+m], blU[kk*4+m]);
            }

        float k1 = FLT_MAX, k2 = FLT_MAX, k3 = FLT_MAX, k4 = FLT_MAX;

        const uint32_t* aH  = apackH + (size_t)j * 32768;
        const uint32_t* aL  = apackL + (size_t)j * 32768;
        const float*    cnj = cnref + (size_t)j * KN;

        #pragma unroll 1
        for (int ch = 0; ch < 32; ++ch) {
            f32x16 acc;
            #pragma unroll
            for (int q = 0; q < 4; ++q) {
                const float4 t = *(const float4*)(cnj + ch * 32 + q * 8 + h * 4);
                acc[4*q+0] = t.x; acc[4*q+1] = t.y; acc[4*q+2] = t.z; acc[4*q+3] = t.w;
            }
            #pragma unroll
            for (int kk = 0; kk < 4; ++kk) {
                AB8 ah_, al_, bh_, bl_;
                ah_.v = *(const uint4*)(aH + (size_t)(ch * 4 + kk) * 256 + lane * 4);
                al_.v = *(const uint4*)(aL + (size_t)(ch * 4 + kk) * 256 + lane * 4);
                bh_.u[0] = bhU[kk*4+0]; bh_.u[1] = bhU[kk*4+1];
                bh_.u[2] = bhU[kk*4+2]; bh_.u[3] = bhU[kk*4+3];
                bl_.u[0] = blU[kk*4+0]; bl_.u[1] = blU[kk*4+1];
                bl_.u[2] = blU[kk*4+2]; bl_.u[3] = blU[kk*4+3];
                acc = __builtin_amdgcn_mfma_f32_32x32x16_f16(ah_.h, bh_.h, acc, 0, 0, 0);
                acc = __builtin_amdgcn_mfma_f32_32x32x16_f16(al_.h, bh_.h, acc, 0, 0, 0);
                acc = __builtin_amdgcn_mfma_f32_32x32x16_f16(ah_.h, bl_.h, acc, 0, 0, 0);
            }
            // packed-key top-4: 4 independent 1-op chains per value
            const uint32_t lb = (uint32_t)(ch * 16);
            #pragma unroll
            for (int q = 0; q < 16; ++q) {
                const uint32_t key = (__float_as_uint(acc[q]) & KEYMASK) | (lb + (uint32_t)q);
                const float kf = __uint_as_float(key);
                k4 = __builtin_amdgcn_fmed3f(kf, k3, k4);
                k3 = __builtin_amdgcn_fmed3f(kf, k2, k3);
                k2 = __builtin_amdgcn_fmed3f(kf, k1, k2);
                k1 = fminf(kf, k1);
            }
        }

        // ---- decode own top-3, merge partner half, adopt lane-l's view ----
        float b1 = k1, b2 = k2, b3 = k3, b4 = k4;
        const int hb = 4 * h, hp = 4 * (1 - h);
        int i1, i2, i3;
        {
            const uint32_t u1 = __float_as_uint(k1) & 511u;
            const uint32_t u2 = __float_as_uint(k2) & 511u;
            const uint32_t u3 = __float_as_uint(k3) & 511u;
            i1 = (int)((u1 >> 4) * 32 + (u1 & 3) + 8 * ((u1 >> 2) & 3)) + hb;
            i2 = (int)((u2 >> 4) * 32 + (u2 & 3) + 8 * ((u2 >> 2) & 3)) + hb;
            i3 = (int)((u3 >> 4) * 32 + (u3 & 3) + 8 * ((u3 >> 2) & 3)) + hb;
        }
        {
            const float p1 = __shfl_xor(k1, 32, 64);
            const float p2 = __shfl_xor(k2, 32, 64);
            const float p3 = __shfl_xor(k3, 32, 64);
            const float p4 = __shfl_xor(k4, 32, 64);
            const uint32_t v1 = __float_as_uint(p1) & 511u;
            const uint32_t v2 = __float_as_uint(p2) & 511u;
            const uint32_t v3 = __float_as_uint(p3) & 511u;
            const int pi1 = (int)((v1 >> 4) * 32 + (v1 & 3) + 8 * ((v1 >> 2) & 3)) + hp;
            const int pi2 = (int)((v2 >> 4) * 32 + (v2 & 3) + 8 * ((v2 >> 2) & 3)) + hp;
            const int pi3 = (int)((v3 >> 4) * 32 + (v3 & 3) + 8 * ((v3 >> 2) & 3)) + hp;
            INS4IX(p1, pi1);
            INS4IX(p2, pi2);
            INS4IX(p3, pi3);
            INS4IX(p4, 0);   // partner's 4th can never enter merged top-3 (>=3 values below)
        }
        {   // adopt lane (l&31)'s merged view -> pair-deterministic results
            const int src = lane & 31;
            b1 = __shfl(b1, src, 64); b2 = __shfl(b2, src, 64);
            b3 = __shfl(b3, src, 64); b4 = __shfl(b4, src, 64);
            i1 = __shfl(i1, src, 64); i2 = __shfl(i2, src, 64); i3 = __shfl(i3, src, 64);
        }

        int chosen = i1;
        const bool near_ = (b2 - b1 < MARGIN);
        const bool deep  = near_ && ((b4 - b1 < MARGIN) || (fabsf(b1) >= B1CAP));

        if (__builtin_expect(near_ && !deep, 0)) {
            // ---- light exact rescore of {i1,i2,i3}: all from registers ----
            float rl_[32], po[32];
            #pragma unroll
            for (int t = 0; t < 32; ++t) rl_[t] = __fsub_rn(x_[t], q_[t]);
            #pragma unroll
            for (int t = 0; t < 32; ++t) po[t] = __shfl_xor(rl_[t], 32, 64);
            float rex[DN];
            #pragma unroll
            for (int kk = 0; kk < 4; ++kk)
                #pragma unroll
                for (int e = 0; e < 8; ++e) {
                    rex[kk*16 + e]     = h ? po[kk*8+e]  : rl_[kk*8+e];
                    rex[kk*16 + 8 + e] = h ? rl_[kk*8+e] : po[kk*8+e];
                }
            const float rr = rr_tree(rex);

            const float* cbj = cb + (size_t)j * KN * DN;
            const float* c0p = cbj + (size_t)i1 * DN;
            const float* c1p = cbj + (size_t)i2 * DN;
            const float* c2p = cbj + (size_t)i3 * DN;
            float cr0 = 0.f, cr1 = 0.f, cr2 = 0.f;
            #pragma unroll
            for (int d4 = 0; d4 < DN / 4; ++d4) {
                const float4 a = *(const float4*)(c0p + 4 * d4);
                const float4 b = *(const float4*)(c1p + 4 * d4);
                const float4 c = *(const float4*)(c2p + 4 * d4);
                const float r0 = rex[4*d4+0], r1 = rex[4*d4+1];
                const float r2 = rex[4*d4+2], r3 = rex[4*d4+3];
                cr0 = __fmaf_rn(r0, a.x, cr0); cr1 = __fmaf_rn(r0, b.x, cr1); cr2 = __fmaf_rn(r0, c.x, cr2);
                cr0 = __fmaf_rn(r1, a.y, cr0); cr1 = __fmaf_rn(r1, b.y, cr1); cr2 = __fmaf_rn(r1, c.y, cr2);
                cr0 = __fmaf_rn(r2, a.z, cr0); cr1 = __fmaf_rn(r2, b.z, cr1); cr2 = __fmaf_rn(r2, c.z, cr2);
                cr0 = __fmaf_rn(r3, a.w, cr0); cr1 = __fmaf_rn(r3, b.w, cr1); cr2 = __fmaf_rn(r3, c.w, cr2);
            }
            const float d2c0 = __fadd_rn(__fsub_rn(rr, __fmul_rn(2.0f, cr0)), cnj[i1]);
            const float d2c1 = __fadd_rn(__fsub_rn(rr, __fmul_rn(2.0f, cr1)), cnj[i2]);
            const float d2c2 = __fadd_rn(__fsub_rn(rr, __fmul_rn(2.0f, cr2)), cnj[i3]);
            float bd = d2c0; int bk = i1;
            if (d2c1 < bd || (d2c1 == bd && i2 < bk)) { bd = d2c1; bk = i2; }
            if (d2c2 < bd || (d2c2 == bd && i3 < bk)) { bd = d2c2; bk = i3; }
            chosen = bk;
        }

        // ---- deep: wave-cooperative exact full scan (rare) ----
        unsigned long long dm = __ballot(deep) & 0xFFFFFFFFull;
        while (__builtin_expect(dm != 0ull, 0)) {
            const int p = __ffsll((long long)dm) - 1; dm &= dm - 1;
            // broadcast the pair's exact residual (frozen fsub chain values)
            float rex[DN];
            #pragma unroll
            for (int kk = 0; kk < 4; ++kk)
                #pragma unroll
                for (int e = 0; e < 8; ++e) {
                    const float vloc = __fsub_rn(x_[kk*8+e], q_[kk*8+e]);
                    rex[kk*16 + e]     = __shfl(vloc, p, 64);
                    rex[kk*16 + 8 + e] = __shfl(vloc, p + 32, 64);
                }
            const float rr = rr_tree(rex);
            const float* cbj = cb + (size_t)j * KN * DN;
            const int k0 = lane * 16;
            const float4* cn4 = (const float4*)(cnj + k0);
            float bd = FLT_MAX; int bk = 0;
            #pragma unroll 1
            for (int t = 0; t < 16; ++t) {
                const float* cp = cbj + (size_t)(k0 + t) * DN;
                float cr = 0.f;
                #pragma unroll
                for (int d4 = 0; d4 < DN / 4; ++d4) {
                    const float4 a = *(const float4*)(cp + 4 * d4);
                    cr = __fmaf_rn(rex[4*d4+0], a.x, cr);
                    cr = __fmaf_rn(rex[4*d4+1], a.y, cr);
                    cr = __fmaf_rn(rex[4*d4+2], a.z, cr);
                    cr = __fmaf_rn(rex[4*d4+3], a.w, cr);
                }
                const float cnv = ((const float*)cn4)[t];
                const float d2 = __fadd_rn(__fsub_rn(rr, __fmul_rn(2.0f, cr)), cnv);
                if (d2 < bd) { bd = d2; bk = k0 + t; }
            }
            // lexicographic (d2, k) butterfly min == ascending-k first-min semantics
            #pragma unroll
            for (int off = 32; off; off >>= 1) {
                const float od = __shfl_xor(bd, off, 64);
                const int   ok = __shfl_xor(bk, off, 64);
                if (od < bd || (od == bd && ok < bk)) { bd = od; bk = ok; }
            }
            if ((lane & 31) == p) chosen = bk;
        }

        codes[j] = chosen;

        // ---- q update: reference-exact fadd chain, own half only ----
        {
            const float* cw = cb + ((size_t)j * KN + chosen) * DN;
            #pragma unroll
            for (int kk = 0; kk < 4; ++kk) {
                const float4 a = *(const float4*)(cw + kk * 16 + 8 * h);
                const float4 b = *(const float4*)(cw + kk * 16 + 8 * h + 4);
                q_[kk*8+0] = __fadd_rn(q_[kk*8+0], a.x);
                q_[kk*8+1] = __fadd_rn(q_[kk*8+1], a.y);
                q_[kk*8+2] = __fadd_rn(q_[kk*8+2], a.z);
                q_[kk*8+3] = __fadd_rn(q_[kk*8+3], a.w);
                q_[kk*8+4] = __fadd_rn(q_[kk*8+4], b.x);
                q_[kk*8+5] = __fadd_rn(q_[kk*8+5], b.y);
                q_[kk*8+6] = __fadd_rn(q_[kk*8+6], b.z);
                q_[kk*8+7] = __fadd_rn(q_[kk*8+7], b.w);
            }
        }
    }

    if (iv < n) {
        if (h == 0) {
            float4 e0, e1;
            e0.x = (float)codes[0]; e0.y = (float)codes[1];
            e0.z = (float)codes[2]; e0.w = (float)codes[3];
            e1.x = (float)codes[4]; e1.y = (float)codes[5];
            e1.z = (float)codes[6]; e1.w = (float)codes[7];
            *(float4*)(out_enc + (size_t)iv * QN)     = e0;
            *(float4*)(out_enc + (size_t)iv * QN + 4) = e1;
        }
        // out_q = q (reference-exact chain); each half writes its own float4 blocks
        float4* qo = (float4*)(out_q + (size_t)iv * DN);
        #pragma unroll
        for (int kk = 0; kk < 4; ++kk) {
            float4 o0, o1;
            o0.x = q_[kk*8+0]; o0.y = q_[kk*8+1]; o0.z = q_[kk*8+2]; o0.w = q_[kk*8+3];
            o1.x = q_[kk*8+4]; o1.y = q_[kk*8+5]; o1.z = q_[kk*8+6]; o1.w = q_[kk*8+7];
            qo[kk*4 + 2*h]     = o0;
            qo[kk*4 + 2*h + 1] = o1;
        }
    }
}

extern "C" void kernel_launch(void* const* d_in, const int* in_sizes, int n_in,
                              void* d_out, int out_size, void* d_ws, size_t ws_size,
                              hipStream_t stream) {
    const float* x   = (const float*)d_in[0];
    const float* cbp = (const float*)d_in[1];
    const int n = in_sizes[0] / DN;

    float* out_enc = (float*)d_out;                   // [N, Q]
    float* out_q   = (float*)d_out + (size_t)n * QN;  // [N, D]

    // workspace: 1 MiB apackH + 1 MiB apackL (fragment-order fp16) + 32 KiB ||c||^2
    uint32_t* apackH = (uint32_t*)d_ws;
    uint32_t* apackL = (uint32_t*)((char*)d_ws + (size_t)QN * KN * DN * 2);
    float*    cn     = (float*)((char*)d_ws + (size_t)QN * KN * DN * 4);

    rvq_prep_kernel<<<dim3((QN * KN + 255) / 256), dim3(256), 0, stream>>>(
        cbp, apackH, apackL, cn);
    rvq_encode_kernel<<<dim3((n + 127) / 128), dim3(256), 0, stream>>>(
        x, cbp, apackH, apackL, cn, out_enc, out_q, n);
}